// Round 11
// baseline (594.488 us; speedup 1.0000x reference)
//
#include <hip/hip_runtime.h>
#include <math.h>

#define HDIM 128
#define G4 512   // 4*H
#define TS 36    // GEMM LDS row stride (floats)
#define SLAB 256 // rows per wave in linear attention sweep
#define WIN 16   // rows per window

typedef float vf4 __attribute__((ext_vector_type(4)));
typedef unsigned short u16x8 __attribute__((ext_vector_type(8)));

__device__ __forceinline__ float sigm(float v) { return 1.0f / (1.0f + __expf(-v)); }
__device__ __forceinline__ float ftanh(float v) {
    return 1.0f - 2.0f / (__expf(2.0f * v) + 1.0f);
}
__device__ __forceinline__ float dot4(vf4 a, vf4 b) {
    return a.x * b.x + a.y * b.y + a.z * b.z + a.w * b.w;
}
__device__ __forceinline__ vf4 ldnt4(const float* p) {
    return __builtin_nontemporal_load((const vf4*)p);
}
__device__ __forceinline__ unsigned short f2bf(float f) {  // RTNE
    unsigned u = __float_as_uint(f);
    u += 0x7fff + ((u >> 16) & 1);
    return (unsigned short)(u >> 16);
}
__device__ __forceinline__ float bf2f(unsigned short h) {
    return __uint_as_float(((unsigned)h) << 16);
}

#define SHFL16(p_)                  \
    p_ += __shfl_xor(p_, 1, 64);    \
    p_ += __shfl_xor(p_, 2, 64);    \
    p_ += __shfl_xor(p_, 4, 64);    \
    p_ += __shfl_xor(p_, 8, 64);

// ---- fast zero of scratch accumulators (hipMemsetAsync's fillBuffer path ran at
// 83 GB/s -> ~300 us for 25 MB; this grid-stride vf4 kernel does it at stream BW)
__global__ __launch_bounds__(256) void k_zero(float* __restrict__ p, long n4) {
    long i = (long)blockIdx.x * 256 + threadIdx.x;
    long stride = (long)gridDim.x * 256;
    vf4 z = {0.f, 0.f, 0.f, 0.f};
    for (; i < n4; i += stride) *(vf4*)(p + i * 4) = z;
}

// ---- setup: Wc prep + segment starts + gh0 (= Wc_h . h0, h0 from biases)
__global__ __launch_bounds__(256) void k_setup(const float* __restrict__ W_ih,
                                               const float* __restrict__ W_hh,
                                               const float* __restrict__ b_ih,
                                               const float* __restrict__ b_hh,
                                               const int* __restrict__ batch_vec, int N, int B,
                                               float* __restrict__ Wc, int* __restrict__ seg_start,
                                               float* __restrict__ gh0) {
    __shared__ float h0s[HDIM];
    int t = blockIdx.x * 256 + threadIdx.x;
    if (blockIdx.x < 2) {
        if (threadIdx.x < HDIM) {
            int hid = threadIdx.x;
            float bi = b_ih[hid] + b_hh[hid];
            float bg = b_ih[2 * HDIM + hid] + b_hh[2 * HDIM + hid];
            float bo = b_ih[3 * HDIM + hid] + b_hh[3 * HDIM + hid];
            float c0 = sigm(bi) * ftanh(bg);
            h0s[hid] = sigm(bo) * ftanh(c0);
        }
        __syncthreads();
        if (t < G4) {
            float s = 0.0f;
#pragma unroll
            for (int k = 0; k < HDIM; k += 4) {
                vf4 wi = *(const vf4*)(W_ih + (size_t)t * 256 + k);
                vf4 wh = *(const vf4*)(W_hh + (size_t)t * HDIM + k);
                s += (wi.x + wh.x) * h0s[k] + (wi.y + wh.y) * h0s[k + 1] +
                     (wi.z + wh.z) * h0s[k + 2] + (wi.w + wh.w) * h0s[k + 3];
            }
            gh0[t] = s;
        }
    }
    if (t < G4 * 2 * HDIM) {
        int g = t >> 8;
        int k = t & 255;
        float w = W_ih[g * 256 + k];
        if (k < HDIM) w += W_hh[g * HDIM + k];
        Wc[t] = w;
    }
    if (t <= B) {
        int lo = 0, hi = N;
        while (lo < hi) {
            int mid = (lo + hi) >> 1;
            if (batch_vec[mid] < t) lo = mid + 1; else hi = mid;
        }
        seg_start[t] = lo;
    }
}

// ---- flush one segment's partial (no-max: partials are plain sums)
__device__ __forceinline__ void flush_seg(int seg, int segLo, int segend, int r0, int r1,
                                          float d, vf4 ra, vf4 rb,
                                          float* __restrict__ r_raw, float* __restrict__ d_raw,
                                          int l16, int quarter) {
#pragma unroll
    for (int off = 16; off <= 32; off <<= 1) {  // merge the 4 quarter-partials (adds only)
        d += __shfl_xor(d, off, 64);
        ra.x += __shfl_xor(ra.x, off, 64);
        ra.y += __shfl_xor(ra.y, off, 64);
        ra.z += __shfl_xor(ra.z, off, 64);
        ra.w += __shfl_xor(ra.w, off, 64);
        rb.x += __shfl_xor(rb.x, off, 64);
        rb.y += __shfl_xor(rb.y, off, 64);
        rb.z += __shfl_xor(rb.z, off, 64);
        rb.w += __shfl_xor(rb.w, off, 64);
    }
    if (quarter != 0) return;
    float* rp = r_raw + (size_t)seg * HDIM + l16 * 8;
    if (segLo >= r0 && segend <= r1) {  // segment fully inside this slab: finalize
        float inv = d > 0.f ? 1.f / d : 0.f;
        *(vf4*)rp = ra * inv;
        *(vf4*)(rp + 4) = rb * inv;
        if (l16 == 0) d_raw[seg] = 1.0f;
    } else {  // boundary segment: atomic partial merge
#pragma unroll
        for (int j = 0; j < 4; ++j) {
            atomicAdd(rp + j, ra[j]);
            atomicAdd(rp + 4 + j, rb[j]);
        }
        if (l16 == 0) atomicAdd(d_raw + seg, d);
    }
}

// ---- pass 1: linear slab sweep over fp32 x, fused bf16 conversion, q0 from biases.
__global__ __launch_bounds__(256) void k_attn_lin32(const float* __restrict__ x,
                                                    unsigned short* __restrict__ x16,
                                                    const float* __restrict__ b_ih,
                                                    const float* __restrict__ b_hh,
                                                    const int* __restrict__ seg_start,
                                                    float* __restrict__ r_raw,
                                                    float* __restrict__ d_raw, int N, int B) {
    int wave = threadIdx.x >> 6, lane = threadIdx.x & 63;
    int l16 = lane & 15, quarter = lane >> 4;
    int wid = blockIdx.x * 4 + wave;
    int r0 = wid * SLAB;
    if (r0 >= N) return;
    int r1 = min(r0 + SLAB, N);

    int lo = 0, hi = B - 1;
    while (lo < hi) { int mid = (lo + hi + 1) >> 1; if (seg_start[mid] <= r0) lo = mid; else hi = mid - 1; }
    int seg = lo;
    int segLo = seg_start[seg];
    int segend = seg_start[seg + 1];
    int lowB = r0;

    vf4 qa, qb;  // q0 from biases (same for every segment in pass 1)
    {
        int c = l16 * 8;
        vf4 bi0 = *(const vf4*)(b_ih + c) + *(const vf4*)(b_hh + c);
        vf4 bi1 = *(const vf4*)(b_ih + c + 4) + *(const vf4*)(b_hh + c + 4);
        vf4 bg0 = *(const vf4*)(b_ih + 2 * HDIM + c) + *(const vf4*)(b_hh + 2 * HDIM + c);
        vf4 bg1 = *(const vf4*)(b_ih + 2 * HDIM + c + 4) + *(const vf4*)(b_hh + 2 * HDIM + c + 4);
        vf4 bo0 = *(const vf4*)(b_ih + 3 * HDIM + c) + *(const vf4*)(b_hh + 3 * HDIM + c);
        vf4 bo1 = *(const vf4*)(b_ih + 3 * HDIM + c + 4) + *(const vf4*)(b_hh + 3 * HDIM + c + 4);
#pragma unroll
        for (int j = 0; j < 4; ++j) {
            float c0 = sigm(bi0[j]) * ftanh(bg0[j]);
            qa[j] = sigm(bo0[j]) * ftanh(c0);
            float c1 = sigm(bi1[j]) * ftanh(bg1[j]);
            qb[j] = sigm(bo1[j]) * ftanh(c1);
        }
    }

    float d = 0.f; vf4 ra = {0, 0, 0, 0}, rb = {0, 0, 0, 0};
    int nwin = (r1 - r0 + WIN - 1) / WIN;
    vf4 ca[4], cb[4];
#pragma unroll
    for (int t = 0; t < 4; ++t) {
        int row = min(r0 + quarter + 4 * t, r1 - 1);
        const float* xr = x + (size_t)row * HDIM + l16 * 8;
        ca[t] = ldnt4(xr);
        cb[t] = ldnt4(xr + 4);
    }
#pragma unroll 1
    for (int wnd = 0; wnd < nwin; ++wnd) {
        int base = r0 + wnd * WIN;
        int we = min(base + WIN, r1);
        vf4 na[4], nb[4];
        if (wnd + 1 < nwin) {
#pragma unroll
            for (int t = 0; t < 4; ++t) {
                int row = min(base + WIN + quarter + 4 * t, r1 - 1);
                const float* xr = x + (size_t)row * HDIM + l16 * 8;
                na[t] = ldnt4(xr);
                nb[t] = ldnt4(xr + 4);
            }
        }
        // fused bf16 store (each row written exactly once, by its own window)
#pragma unroll
        for (int t = 0; t < 4; ++t) {
            int row = base + quarter + 4 * t;
            if (row < we) {
                u16x8 cv;
                cv[0] = f2bf(ca[t].x); cv[1] = f2bf(ca[t].y); cv[2] = f2bf(ca[t].z); cv[3] = f2bf(ca[t].w);
                cv[4] = f2bf(cb[t].x); cv[5] = f2bf(cb[t].y); cv[6] = f2bf(cb[t].z); cv[7] = f2bf(cb[t].w);
                *(u16x8*)(x16 + (size_t)row * HDIM + l16 * 8) = cv;
            }
        }
#pragma unroll 1
        while (true) {
            float p[4];
#pragma unroll
            for (int t = 0; t < 4; ++t) p[t] = dot4(ca[t], qa) + dot4(cb[t], qb);
            SHFL16(p[0]) SHFL16(p[1]) SHFL16(p[2]) SHFL16(p[3])
#pragma unroll
            for (int t = 0; t < 4; ++t) {
                int row = base + quarter + 4 * t;
                float w = (row >= lowB && row < segend && row < we) ? __expf(p[t]) : 0.f;
                d += w;
                ra += w * ca[t];
                rb += w * cb[t];
            }
            if (segend >= we) break;
            flush_seg(seg, segLo, segend, r0, r1, d, ra, rb, r_raw, d_raw, l16, quarter);
            lowB = segend; segLo = segend;
            ++seg;
            segend = seg_start[seg + 1];
            d = 0.f; ra = vf4{0, 0, 0, 0}; rb = vf4{0, 0, 0, 0};
        }
#pragma unroll
        for (int t = 0; t < 4; ++t) { ca[t] = na[t]; cb[t] = nb[t]; }
    }
    flush_seg(seg, segLo, segend, r0, r1, d, ra, rb, r_raw, d_raw, l16, quarter);
}

// ---- passes 2,3: linear slab sweep over bf16 x16, q gathered per segment.
__global__ __launch_bounds__(256) void k_attn_lin16(const unsigned short* __restrict__ x16,
                                                    const float* __restrict__ q, int ldq,
                                                    const int* __restrict__ seg_start,
                                                    float* __restrict__ r_raw,
                                                    float* __restrict__ d_raw, int N, int B) {
    int wave = threadIdx.x >> 6, lane = threadIdx.x & 63;
    int l16 = lane & 15, quarter = lane >> 4;
    int wid = blockIdx.x * 4 + wave;
    int r0 = wid * SLAB;
    if (r0 >= N) return;
    int r1 = min(r0 + SLAB, N);

    int lo = 0, hi = B - 1;
    while (lo < hi) { int mid = (lo + hi + 1) >> 1; if (seg_start[mid] <= r0) lo = mid; else hi = mid - 1; }
    int seg = lo;
    int segLo = seg_start[seg];
    int segend = seg_start[seg + 1];
    int lowB = r0;

    vf4 qa, qb;
    {
        const float* qr = q + (size_t)seg * ldq + l16 * 8;
        qa = *(const vf4*)qr; qb = *(const vf4*)(qr + 4);
    }

    float d = 0.f; vf4 ra = {0, 0, 0, 0}, rb = {0, 0, 0, 0};
    int nwin = (r1 - r0 + WIN - 1) / WIN;
    u16x8 cur[4], nxt[4];
#pragma unroll
    for (int t = 0; t < 4; ++t) {
        int row = min(r0 + quarter + 4 * t, r1 - 1);
        cur[t] = *(const u16x8*)(x16 + (size_t)row * HDIM + l16 * 8);
    }
#pragma unroll 1
    for (int wnd = 0; wnd < nwin; ++wnd) {
        int base = r0 + wnd * WIN;
        int we = min(base + WIN, r1);
        if (wnd + 1 < nwin) {
#pragma unroll
            for (int t = 0; t < 4; ++t) {
                int row = min(base + WIN + quarter + 4 * t, r1 - 1);
                nxt[t] = *(const u16x8*)(x16 + (size_t)row * HDIM + l16 * 8);
            }
        }
        vf4 xa[4], xb[4];
#pragma unroll
        for (int t = 0; t < 4; ++t) {
            xa[t] = vf4{bf2f(cur[t][0]), bf2f(cur[t][1]), bf2f(cur[t][2]), bf2f(cur[t][3])};
            xb[t] = vf4{bf2f(cur[t][4]), bf2f(cur[t][5]), bf2f(cur[t][6]), bf2f(cur[t][7])};
        }
#pragma unroll 1
        while (true) {
            float p[4];
#pragma unroll
            for (int t = 0; t < 4; ++t) p[t] = dot4(xa[t], qa) + dot4(xb[t], qb);
            SHFL16(p[0]) SHFL16(p[1]) SHFL16(p[2]) SHFL16(p[3])
#pragma unroll
            for (int t = 0; t < 4; ++t) {
                int row = base + quarter + 4 * t;
                float w = (row >= lowB && row < segend && row < we) ? __expf(p[t]) : 0.f;
                d += w;
                ra += w * xa[t];
                rb += w * xb[t];
            }
            if (segend >= we) break;
            flush_seg(seg, segLo, segend, r0, r1, d, ra, rb, r_raw, d_raw, l16, quarter);
            lowB = segend; segLo = segend;
            ++seg;
            segend = seg_start[seg + 1];
            {
                const float* qr = q + (size_t)seg * ldq + l16 * 8;
                qa = *(const vf4*)qr; qb = *(const vf4*)(qr + 4);
            }
            d = 0.f; ra = vf4{0, 0, 0, 0}; rb = vf4{0, 0, 0, 0};
        }
#pragma unroll
        for (int t = 0; t < 4; ++t) cur[t] = nxt[t];
    }
    flush_seg(seg, segLo, segend, r0, r1, d, ra, rb, r_raw, d_raw, l16, quarter);
}

// ---- step-1 GEMM + LSTM: K=128 (r only); normalization of r folded into A-staging.
__global__ __launch_bounds__(256) void k_gemm_lstm1(const float* __restrict__ r_raw,
                                                    const float* __restrict__ d_raw,
                                                    const float* __restrict__ Wc,
                                                    const float* __restrict__ gh0,
                                                    const float* __restrict__ b_ih,
                                                    const float* __restrict__ b_hh,
                                                    float* __restrict__ h_new,
                                                    float* __restrict__ c_new) {
    __shared__ float As[128 * TS];
    __shared__ float Ws[64 * TS];
    __shared__ float ds[128];
    int ct = blockIdx.y;
    int rb = blockIdx.x * 128;
    int tid = threadIdx.x;
    int tx = tid & 15, ty = tid >> 4;
    if (tid < 128) {
        float dv = d_raw[rb + tid];
        ds[tid] = dv > 0.f ? 1.f / dv : 0.f;
    }
    __syncthreads();
    float acc[8][4];
#pragma unroll
    for (int i = 0; i < 8; ++i)
#pragma unroll
        for (int j = 0; j < 4; ++j) acc[i][j] = 0.0f;

    for (int kc = 0; kc < 4; ++kc) {
        int kbase = kc * 32;
#pragma unroll
        for (int i = 0; i < 4; ++i) {
            int li = tid + i * 256;
            int row = li >> 3;
            int c4 = (li & 7) * 4;
            vf4 v = *(const vf4*)(r_raw + (size_t)(rb + row) * HDIM + kbase + c4);
            *(vf4*)&As[row * TS + c4] = v * ds[row];
        }
#pragma unroll
        for (int i = 0; i < 2; ++i) {
            int li = tid + i * 256;
            int col = li >> 3;
            int c4 = (li & 7) * 4;
            int g = ct * 16 + (col & 15) + 128 * (col >> 4);
            *(vf4*)&Ws[col * TS + c4] = *(const vf4*)(Wc + (size_t)g * 256 + 128 + kbase + c4);
        }
        __syncthreads();
#pragma unroll
        for (int k = 0; k < 32; k += 4) {
            vf4 a[8], b[4];
#pragma unroll
            for (int i = 0; i < 8; ++i) a[i] = *(vf4*)&As[(ty + 16 * i) * TS + k];
#pragma unroll
            for (int j = 0; j < 4; ++j) b[j] = *(vf4*)&Ws[(tx + 16 * j) * TS + k];
#pragma unroll
            for (int i = 0; i < 8; ++i)
#pragma unroll
                for (int j = 0; j < 4; ++j) {
                    acc[i][j] += a[i].x * b[j].x + a[i].y * b[j].y +
                                 a[i].z * b[j].z + a[i].w * b[j].w;
                }
        }
        __syncthreads();
    }
    int hidx = ct * 16 + tx;
    float bi = b_ih[hidx] + b_hh[hidx] + gh0[hidx];
    float bf = b_ih[HDIM + hidx] + b_hh[HDIM + hidx] + gh0[HDIM + hidx];
    float bg = b_ih[2 * HDIM + hidx] + b_hh[2 * HDIM + hidx] + gh0[2 * HDIM + hidx];
    float bo = b_ih[3 * HDIM + hidx] + b_hh[3 * HDIM + hidx] + gh0[3 * HDIM + hidx];
    float bi0 = b_ih[hidx] + b_hh[hidx];
    float bg0 = b_ih[2 * HDIM + hidx] + b_hh[2 * HDIM + hidx];
    float c0 = sigm(bi0) * ftanh(bg0);
#pragma unroll
    for (int i = 0; i < 8; ++i) {
        int row = rb + ty + 16 * i;
        float gi = acc[i][0] + bi;
        float gf = acc[i][1] + bf;
        float gg = acc[i][2] + bg;
        float go = acc[i][3] + bo;
        float cn = sigm(gf) * c0 + sigm(gi) * ftanh(gg);
        float hn = sigm(go) * ftanh(cn);
        c_new[(size_t)row * HDIM + hidx] = cn;
        h_new[(size_t)row * HDIM + hidx] = hn;
    }
}

// ---- step-2 GEMM + LSTM: K=256 (h | r_normalized); h written into out[:, :128].
__global__ __launch_bounds__(256) void k_gemm_lstm(const float* __restrict__ h_prev,
                                                   const float* __restrict__ r_raw,
                                                   const float* __restrict__ d_raw,
                                                   const float* __restrict__ c_prev,
                                                   const float* __restrict__ Wc,
                                                   const float* __restrict__ b_ih,
                                                   const float* __restrict__ b_hh,
                                                   float* __restrict__ h_mirror) {
    __shared__ float As[128 * TS];
    __shared__ float Ws[64 * TS];
    __shared__ float ds[128];
    int ct = blockIdx.y;
    int rb = blockIdx.x * 128;
    int tid = threadIdx.x;
    int tx = tid & 15, ty = tid >> 4;
    if (tid < 128) {
        float dv = d_raw[rb + tid];
        ds[tid] = dv > 0.f ? 1.f / dv : 0.f;
    }
    __syncthreads();
    float acc[8][4];
#pragma unroll
    for (int i = 0; i < 8; ++i)
#pragma unroll
        for (int j = 0; j < 4; ++j) acc[i][j] = 0.0f;

    for (int kc = 0; kc < 8; ++kc) {
        const float* src = (kc < 4) ? h_prev : r_raw;
        int kbase = (kc & 3) * 32;
#pragma unroll
        for (int i = 0; i < 4; ++i) {
            int li = tid + i * 256;
            int row = li >> 3;
            int c4 = (li & 7) * 4;
            vf4 v = *(const vf4*)(src + (size_t)(rb + row) * HDIM + kbase + c4);
            if (kc >= 4) v *= ds[row];
            *(vf4*)&As[row * TS + c4] = v;
        }
#pragma unroll
        for (int i = 0; i < 2; ++i) {
            int li = tid + i * 256;
            int col = li >> 3;
            int c4 = (li & 7) * 4;
            int g = ct * 16 + (col & 15) + 128 * (col >> 4);
            *(vf4*)&Ws[col * TS + c4] = *(const vf4*)(Wc + (size_t)g * 256 + kc * 32 + c4);
        }
        __syncthreads();
#pragma unroll
        for (int k = 0; k < 32; k += 4) {
            vf4 a[8], b[4];
#pragma unroll
            for (int i = 0; i < 8; ++i) a[i] = *(vf4*)&As[(ty + 16 * i) * TS + k];
#pragma unroll
            for (int j = 0; j < 4; ++j) b[j] = *(vf4*)&Ws[(tx + 16 * j) * TS + k];
#pragma unroll
            for (int i = 0; i < 8; ++i)
#pragma unroll
                for (int j = 0; j < 4; ++j) {
                    acc[i][j] += a[i].x * b[j].x + a[i].y * b[j].y +
                                 a[i].z * b[j].z + a[i].w * b[j].w;
                }
        }
        __syncthreads();
    }
    int hidx = ct * 16 + tx;
    float bi = b_ih[hidx] + b_hh[hidx];
    float bf = b_ih[HDIM + hidx] + b_hh[HDIM + hidx];
    float bg = b_ih[2 * HDIM + hidx] + b_hh[2 * HDIM + hidx];
    float bo = b_ih[3 * HDIM + hidx] + b_hh[3 * HDIM + hidx];
#pragma unroll
    for (int i = 0; i < 8; ++i) {
        int row = rb + ty + 16 * i;
        float gi = acc[i][0] + bi;
        float gf = acc[i][1] + bf;
        float gg = acc[i][2] + bg;
        float go = acc[i][3] + bo;
        float cp = c_prev[(size_t)row * HDIM + hidx];
        float cn = sigm(gf) * cp + sigm(gi) * ftanh(gg);
        float hn = sigm(go) * ftanh(cn);
        h_mirror[(size_t)row * 2 * HDIM + hidx] = hn;
    }
}

// ---- final normalize of pass-3 partials into out[:, 128:]
__global__ __launch_bounds__(256) void k_norm(const float* __restrict__ r_raw,
                                              const float* __restrict__ d_raw,
                                              float* __restrict__ out, int B) {
    int idx = blockIdx.x * 256 + threadIdx.x;
    if (idx >= B * HDIM) return;
    int seg = idx >> 7, c = idx & 127;
    float dv = d_raw[seg];
    float inv = dv > 0.f ? 1.f / dv : 0.f;
    out[(size_t)seg * 2 * HDIM + HDIM + c] = r_raw[idx] * inv;
}

extern "C" void kernel_launch(void* const* d_in, const int* in_sizes, int n_in,
                              void* d_out, int out_size, void* d_ws, size_t ws_size,
                              hipStream_t stream) {
    const float* x = (const float*)d_in[0];
    const int* batch_vec = (const int*)d_in[1];
    const float* W_ih = (const float*)d_in[2];
    const float* W_hh = (const float*)d_in[3];
    const float* b_ih = (const float*)d_in[4];
    const float* b_hh = (const float*)d_in[5];
    float* out = (float*)d_out;

    int N = in_sizes[1];
    int B = out_size / (2 * HDIM);

    char* ws = (char*)d_ws;
    float* Wc = (float*)ws;   ws += (size_t)G4 * 2 * HDIM * 4;
    float* gh0 = (float*)ws;  ws += (size_t)G4 * 4;
    float* h_b = (float*)ws;  ws += (size_t)B * HDIM * 4;
    float* cbuf = (float*)ws; ws += (size_t)B * HDIM * 4;
    int* seg = (int*)ws;      ws += (size_t)(B + 1) * 4;
    ws = (char*)(((size_t)ws + 255) & ~(size_t)255);
    char* raw_base = ws;
    float* rA = (float*)ws;   ws += (size_t)B * HDIM * 4;
    float* rB = (float*)ws;   ws += (size_t)B * HDIM * 4;
    float* rC = (float*)ws;   ws += (size_t)B * HDIM * 4;
    float* dA = (float*)ws;   ws += (size_t)B * 4;
    float* dB = (float*)ws;   ws += (size_t)B * 4;
    float* dC = (float*)ws;   ws += (size_t)B * 4;
    size_t raw_bytes = (size_t)(ws - raw_base);
    ws = (char*)(((size_t)ws + 255) & ~(size_t)255);
    unsigned short* x16 = (unsigned short*)ws;  // N*128*2 = 256 MB

    k_zero<<<1024, 256, 0, stream>>>((float*)raw_base, (long)(raw_bytes / 16));
    k_setup<<<512, 256, 0, stream>>>(W_ih, W_hh, b_ih, b_hh, batch_vec, N, B, Wc, seg, gh0);

    int nwaves = (N + SLAB - 1) / SLAB;
    int ablk = (nwaves + 3) / 4;
    dim3 ggrid(B / 128, 8);

    k_attn_lin32<<<ablk, 256, 0, stream>>>(x, x16, b_ih, b_hh, seg, rA, dA, N, B);
    k_gemm_lstm1<<<ggrid, 256, 0, stream>>>(rA, dA, Wc, gh0, b_ih, b_hh, h_b, cbuf);
    k_attn_lin16<<<ablk, 256, 0, stream>>>(x16, h_b, HDIM, seg, rB, dB, N, B);
    k_gemm_lstm<<<ggrid, 256, 0, stream>>>(h_b, rB, dB, cbuf, Wc, b_ih, b_hh, out);
    k_attn_lin16<<<ablk, 256, 0, stream>>>(x16, out, 2 * HDIM, seg, rC, dC, N, B);
    k_norm<<<(B * HDIM + 255) / 256, 256, 0, stream>>>(rC, dC, out, B);
}

// Round 12
// 463.520 us; speedup vs baseline: 1.2825x; 1.2825x over previous
//
#include <hip/hip_runtime.h>
#include <math.h>

#define HDIM 128
#define G4 512  // 4*H
#define TS 36   // GEMM LDS row stride (floats)

typedef float vf4 __attribute__((ext_vector_type(4)));
typedef unsigned short u16x8 __attribute__((ext_vector_type(8)));

__device__ __forceinline__ float sigm(float v) { return 1.0f / (1.0f + __expf(-v)); }
__device__ __forceinline__ float ftanh(float v) {
    return 1.0f - 2.0f / (__expf(2.0f * v) + 1.0f);
}
__device__ __forceinline__ float dot4(vf4 a, vf4 b) {
    return a.x * b.x + a.y * b.y + a.z * b.z + a.w * b.w;
}
__device__ __forceinline__ vf4 ldnt4(const float* p) {
    return __builtin_nontemporal_load((const vf4*)p);
}
__device__ __forceinline__ unsigned short f2bf(float f) {  // RTNE
    unsigned u = __float_as_uint(f);
    u += 0x7fff + ((u >> 16) & 1);
    return (unsigned short)(u >> 16);
}
__device__ __forceinline__ float bf2f(unsigned short h) {
    return __uint_as_float(((unsigned)h) << 16);
}

// ---- setup: Wc prep + segment starts + gh0 (= Wc_h . h0, h0 from biases)
__global__ __launch_bounds__(256) void k_setup(const float* __restrict__ W_ih,
                                               const float* __restrict__ W_hh,
                                               const float* __restrict__ b_ih,
                                               const float* __restrict__ b_hh,
                                               const int* __restrict__ batch_vec, int N, int B,
                                               float* __restrict__ Wc, int* __restrict__ seg_start,
                                               float* __restrict__ gh0) {
    __shared__ float h0s[HDIM];
    int t = blockIdx.x * 256 + threadIdx.x;
    if (blockIdx.x < 2) {
        if (threadIdx.x < HDIM) {
            int hid = threadIdx.x;
            float bi = b_ih[hid] + b_hh[hid];
            float bg = b_ih[2 * HDIM + hid] + b_hh[2 * HDIM + hid];
            float bo = b_ih[3 * HDIM + hid] + b_hh[3 * HDIM + hid];
            float c0 = sigm(bi) * ftanh(bg);
            h0s[hid] = sigm(bo) * ftanh(c0);
        }
        __syncthreads();
        if (t < G4) {
            float s = 0.0f;
#pragma unroll
            for (int k = 0; k < HDIM; k += 4) {
                vf4 wi = *(const vf4*)(W_ih + (size_t)t * 256 + k);
                vf4 wh = *(const vf4*)(W_hh + (size_t)t * HDIM + k);
                s += (wi.x + wh.x) * h0s[k] + (wi.y + wh.y) * h0s[k + 1] +
                     (wi.z + wh.z) * h0s[k + 2] + (wi.w + wh.w) * h0s[k + 3];
            }
            gh0[t] = s;
        }
    }
    if (t < G4 * 2 * HDIM) {
        int g = t >> 8;
        int k = t & 255;
        float w = W_ih[g * 256 + k];
        if (k < HDIM) w += W_hh[g * HDIM + k];
        Wc[t] = w;
    }
    if (t <= B) {
        int lo = 0, hi = N;
        while (lo < hi) {
            int mid = (lo + hi) >> 1;
            if (batch_vec[mid] < t) lo = mid + 1; else hi = mid;
        }
        seg_start[t] = lo;
    }
}

#define UPD(m_, d_, ra_, rb_, p_, xa_, xb_)  \
    {                                        \
        float mn_ = fmaxf(m_, p_);           \
        float sc_ = __expf(m_ - mn_);        \
        float pe_ = __expf(p_ - mn_);        \
        d_ = d_ * sc_ + pe_;                 \
        ra_ = ra_ * sc_ + pe_ * xa_;         \
        rb_ = rb_ * sc_ + pe_ * xb_;         \
        m_ = mn_;                            \
    }

#define SHFL16(p_)                  \
    p_ += __shfl_xor(p_, 1, 64);    \
    p_ += __shfl_xor(p_, 2, 64);    \
    p_ += __shfl_xor(p_, 4, 64);    \
    p_ += __shfl_xor(p_, 8, 64);

struct AttState {
    float m0, d0, m1, d1;
    vf4 ra0, rb0, ra1, rb1;
};

__device__ __forceinline__ void init_state(AttState& st) {
    st.m0 = 0.f; st.d0 = 0.f; st.m1 = 0.f; st.d1 = 0.f;
    st.ra0 = vf4{0.f, 0.f, 0.f, 0.f}; st.rb0 = vf4{0.f, 0.f, 0.f, 0.f};
    st.ra1 = vf4{0.f, 0.f, 0.f, 0.f}; st.rb1 = vf4{0.f, 0.f, 0.f, 0.f};
}

__device__ __forceinline__ void compute4(const vf4 xa[4], const vf4 xb[4], int baserow, int e,
                                         vf4 qa, vf4 qb, AttState& st) {
    float p[4];
#pragma unroll
    for (int t = 0; t < 4; ++t) p[t] = dot4(xa[t], qa) + dot4(xb[t], qb);
    SHFL16(p[0]) SHFL16(p[1]) SHFL16(p[2]) SHFL16(p[3])
#pragma unroll
    for (int t = 0; t < 4; ++t)
        if (baserow + t >= e) p[t] = -1e30f;
    UPD(st.m0, st.d0, st.ra0, st.rb0, p[0], xa[0], xb[0])
    UPD(st.m1, st.d1, st.ra1, st.rb1, p[1], xa[1], xb[1])
    UPD(st.m0, st.d0, st.ra0, st.rb0, p[2], xa[2], xb[2])
    UPD(st.m1, st.d1, st.ra1, st.rb1, p[3], xa[3], xb[3])
}

__device__ __forceinline__ void finish_state(AttState& st, float* dst) {
    float M = fmaxf(st.m0, st.m1);
    float w0 = __expf(st.m0 - M), w1 = __expf(st.m1 - M);
    float d = st.d0 * w0 + st.d1 * w1;
    vf4 ra = st.ra0 * w0 + st.ra1 * w1;
    vf4 rb = st.rb0 * w0 + st.rb1 * w1;
    float inv = (d > 0.0f) ? 1.0f / d : 0.0f;
    *(vf4*)dst = ra * inv;
    *(vf4*)(dst + 4) = rb * inv;
}

// segment geometry for quarter-per-segment layout (4 segs/wave, 16/block)
__device__ __forceinline__ int seg_of_block(int bid, int nblk, int rev, int wave, int quarter) {
    int q8 = nblk >> 3, r8 = nblk & 7;
    int xcd = bid & 7, pos = bid >> 3;
    int nb = (xcd < r8 ? xcd * (q8 + 1) : r8 * (q8 + 1) + (xcd - r8) * q8) + pos;
    if (rev) nb = nblk - 1 - nb;
    return nb * 16 + wave * 4 + quarter;
}

// ---- pass 1: fp32 x attention + fused bf16 conversion; q0 from biases.
// Quarter-per-segment, 2-stage software pipeline (R9-proven form).
__global__ __launch_bounds__(256) void k_attn_cvt(const float* __restrict__ x,
                                                  unsigned short* __restrict__ x16,
                                                  const float* __restrict__ b_ih,
                                                  const float* __restrict__ b_hh,
                                                  const int* __restrict__ seg_start,
                                                  float* __restrict__ r_out, int B) {
    int wave = threadIdx.x >> 6;
    int lane = threadIdx.x & 63;
    int l16 = lane & 15;
    int quarter = lane >> 4;
    int seg = seg_of_block(blockIdx.x, gridDim.x, 0, wave, quarter);
    int seg_c = min(seg, B - 1);
    int s = seg_start[seg_c], e = seg_start[seg_c + 1];
    if (seg >= B) { s = 0; e = 0; }

    vf4 qa, qb;
    {  // q0 from biases (step-0 LSTM with h=c=0)
        int c = l16 * 8;
        vf4 bi0 = *(const vf4*)(b_ih + c) + *(const vf4*)(b_hh + c);
        vf4 bi1 = *(const vf4*)(b_ih + c + 4) + *(const vf4*)(b_hh + c + 4);
        vf4 bg0 = *(const vf4*)(b_ih + 2 * HDIM + c) + *(const vf4*)(b_hh + 2 * HDIM + c);
        vf4 bg1 = *(const vf4*)(b_ih + 2 * HDIM + c + 4) + *(const vf4*)(b_hh + 2 * HDIM + c + 4);
        vf4 bo0 = *(const vf4*)(b_ih + 3 * HDIM + c) + *(const vf4*)(b_hh + 3 * HDIM + c);
        vf4 bo1 = *(const vf4*)(b_ih + 3 * HDIM + c + 4) + *(const vf4*)(b_hh + 3 * HDIM + c + 4);
#pragma unroll
        for (int j = 0; j < 4; ++j) {
            float c0 = sigm(bi0[j]) * ftanh(bg0[j]);
            qa[j] = sigm(bo0[j]) * ftanh(c0);
            float c1 = sigm(bi1[j]) * ftanh(bg1[j]);
            qb[j] = sigm(bo1[j]) * ftanh(c1);
        }
    }

    int iters = (e - s + 3) >> 2;
    iters = max(iters, __shfl_xor(iters, 16, 64));
    iters = max(iters, __shfl_xor(iters, 32, 64));
    iters = max(iters, 1);

    AttState st;
    init_state(st);

    vf4 ca[4], cb[4];
#pragma unroll
    for (int t = 0; t < 4; ++t) {
        int rl = max(min(s + t, e - 1), 0);
        const float* xr = x + (size_t)rl * HDIM + l16 * 8;
        ca[t] = ldnt4(xr);
        cb[t] = ldnt4(xr + 4);
    }
    int base = s;
#pragma unroll 1
    for (int j = 1; j < iters; ++j) {
        vf4 na[4], nb[4];
#pragma unroll
        for (int t = 0; t < 4; ++t) {
            int rl = max(min(s + 4 * j + t, e - 1), 0);
            const float* xr = x + (size_t)rl * HDIM + l16 * 8;
            na[t] = ldnt4(xr);
            nb[t] = ldnt4(xr + 4);
        }
#pragma unroll
        for (int t = 0; t < 4; ++t) {
            if (base + t < e) {
                u16x8 cv;
                cv[0] = f2bf(ca[t].x); cv[1] = f2bf(ca[t].y); cv[2] = f2bf(ca[t].z); cv[3] = f2bf(ca[t].w);
                cv[4] = f2bf(cb[t].x); cv[5] = f2bf(cb[t].y); cv[6] = f2bf(cb[t].z); cv[7] = f2bf(cb[t].w);
                *(u16x8*)(x16 + (size_t)(base + t) * HDIM + l16 * 8) = cv;
            }
        }
        compute4(ca, cb, base, e, qa, qb, st);
#pragma unroll
        for (int t = 0; t < 4; ++t) { ca[t] = na[t]; cb[t] = nb[t]; }
        base += 4;
    }
#pragma unroll
    for (int t = 0; t < 4; ++t) {
        if (base + t < e) {
            u16x8 cv;
            cv[0] = f2bf(ca[t].x); cv[1] = f2bf(ca[t].y); cv[2] = f2bf(ca[t].z); cv[3] = f2bf(ca[t].w);
            cv[4] = f2bf(cb[t].x); cv[5] = f2bf(cb[t].y); cv[6] = f2bf(cb[t].z); cv[7] = f2bf(cb[t].w);
            *(u16x8*)(x16 + (size_t)(base + t) * HDIM + l16 * 8) = cv;
        }
    }
    compute4(ca, cb, base, e, qa, qb, st);

    if (seg < B) finish_state(st, r_out + (size_t)seg * HDIM + l16 * 8);
}

// ---- passes 2,3: bf16 x attention, quarter-per-segment, DEPTH-2 pipeline
// (3 buffers, unroll-by-3 static rotation; overrun windows fully masked).
#define LOADW(buf_, wi_)                                                      \
    _Pragma("unroll")                                                         \
    for (int t = 0; t < 4; ++t) {                                             \
        int rl = max(min(s + 4 * (wi_) + t, e - 1), 0);                       \
        buf_[t] = *(const u16x8*)(x16 + (size_t)rl * HDIM + l16 * 8);         \
    }

#define COMPW(buf_, wi_)                                                      \
    {                                                                         \
        vf4 xa[4], xb[4];                                                     \
        _Pragma("unroll")                                                     \
        for (int t = 0; t < 4; ++t) {                                         \
            xa[t] = vf4{bf2f(buf_[t][0]), bf2f(buf_[t][1]),                   \
                        bf2f(buf_[t][2]), bf2f(buf_[t][3])};                  \
            xb[t] = vf4{bf2f(buf_[t][4]), bf2f(buf_[t][5]),                   \
                        bf2f(buf_[t][6]), bf2f(buf_[t][7])};                  \
        }                                                                     \
        compute4(xa, xb, s + 4 * (wi_), e, qa, qb, st);                       \
    }

__global__ __launch_bounds__(256) void k_attn_b16(const unsigned short* __restrict__ x16,
                                                  const float* __restrict__ q, int ldq,
                                                  const int* __restrict__ seg_start,
                                                  float* __restrict__ r_out, int ldr, int col_off,
                                                  int B, int rev) {
    int wave = threadIdx.x >> 6;
    int lane = threadIdx.x & 63;
    int l16 = lane & 15;
    int quarter = lane >> 4;
    int seg = seg_of_block(blockIdx.x, gridDim.x, rev, wave, quarter);
    int seg_c = min(seg, B - 1);
    int s = seg_start[seg_c], e = seg_start[seg_c + 1];
    if (seg >= B) { s = 0; e = 0; }

    const float* qrow = q + (size_t)seg_c * ldq + l16 * 8;
    vf4 qa = *(const vf4*)qrow;
    vf4 qb = *(const vf4*)(qrow + 4);

    int iters = (e - s + 3) >> 2;
    iters = max(iters, __shfl_xor(iters, 16, 64));
    iters = max(iters, __shfl_xor(iters, 32, 64));
    iters = max(iters, 1);
    int iters3 = (iters + 2) / 3;  // macro-iterations of 3 windows

    AttState st;
    init_state(st);

    u16x8 bufA[4], bufB[4], bufC[4];
    LOADW(bufA, 0)
    LOADW(bufB, 1)
    int w = 0;
#pragma unroll 1
    for (int mj = 0; mj < iters3; ++mj) {
        LOADW(bufC, w + 2)
        COMPW(bufA, w)
        LOADW(bufA, w + 3)
        COMPW(bufB, w + 1)
        LOADW(bufB, w + 4)
        COMPW(bufC, w + 2)
        w += 3;
    }

    if (seg < B) finish_state(st, r_out + (size_t)seg * ldr + col_off + l16 * 8);
}

// ---- step-1 GEMM + LSTM: K=128 (r only); gh0 folded into bias; c0 recomputed.
__global__ __launch_bounds__(256) void k_gemm_lstm1(const float* __restrict__ r_prev,
                                                    const float* __restrict__ Wc,
                                                    const float* __restrict__ gh0,
                                                    const float* __restrict__ b_ih,
                                                    const float* __restrict__ b_hh,
                                                    float* __restrict__ h_new,
                                                    float* __restrict__ c_new) {
    __shared__ float As[128 * TS];
    __shared__ float Ws[64 * TS];
    int ct = blockIdx.y;
    int rb = blockIdx.x * 128;
    int tid = threadIdx.x;
    int tx = tid & 15, ty = tid >> 4;
    float acc[8][4];
#pragma unroll
    for (int i = 0; i < 8; ++i)
#pragma unroll
        for (int j = 0; j < 4; ++j) acc[i][j] = 0.0f;

    for (int kc = 0; kc < 4; ++kc) {
        int kbase = kc * 32;
#pragma unroll
        for (int i = 0; i < 4; ++i) {
            int li = tid + i * 256;
            int row = li >> 3;
            int c4 = (li & 7) * 4;
            *(vf4*)&As[row * TS + c4] = *(const vf4*)(r_prev + (size_t)(rb + row) * HDIM + kbase + c4);
        }
#pragma unroll
        for (int i = 0; i < 2; ++i) {
            int li = tid + i * 256;
            int col = li >> 3;
            int c4 = (li & 7) * 4;
            int g = ct * 16 + (col & 15) + 128 * (col >> 4);
            *(vf4*)&Ws[col * TS + c4] = *(const vf4*)(Wc + (size_t)g * 256 + 128 + kbase + c4);
        }
        __syncthreads();
#pragma unroll
        for (int k = 0; k < 32; k += 4) {
            vf4 a[8], b[4];
#pragma unroll
            for (int i = 0; i < 8; ++i) a[i] = *(vf4*)&As[(ty + 16 * i) * TS + k];
#pragma unroll
            for (int j = 0; j < 4; ++j) b[j] = *(vf4*)&Ws[(tx + 16 * j) * TS + k];
#pragma unroll
            for (int i = 0; i < 8; ++i)
#pragma unroll
                for (int j = 0; j < 4; ++j) {
                    acc[i][j] += a[i].x * b[j].x + a[i].y * b[j].y +
                                 a[i].z * b[j].z + a[i].w * b[j].w;
                }
        }
        __syncthreads();
    }
    int hidx = ct * 16 + tx;
    float bi = b_ih[hidx] + b_hh[hidx] + gh0[hidx];
    float bf = b_ih[HDIM + hidx] + b_hh[HDIM + hidx] + gh0[HDIM + hidx];
    float bg = b_ih[2 * HDIM + hidx] + b_hh[2 * HDIM + hidx] + gh0[2 * HDIM + hidx];
    float bo = b_ih[3 * HDIM + hidx] + b_hh[3 * HDIM + hidx] + gh0[3 * HDIM + hidx];
    float bi0 = b_ih[hidx] + b_hh[hidx];
    float bg0 = b_ih[2 * HDIM + hidx] + b_hh[2 * HDIM + hidx];
    float c0 = sigm(bi0) * ftanh(bg0);
#pragma unroll
    for (int i = 0; i < 8; ++i) {
        int row = rb + ty + 16 * i;
        float gi = acc[i][0] + bi;
        float gf = acc[i][1] + bf;
        float gg = acc[i][2] + bg;
        float go = acc[i][3] + bo;
        float cn = sigm(gf) * c0 + sigm(gi) * ftanh(gg);
        float hn = sigm(go) * ftanh(cn);
        c_new[(size_t)row * HDIM + hidx] = cn;
        h_new[(size_t)row * HDIM + hidx] = hn;
    }
}

// ---- step-2 GEMM + LSTM: K=256 (h | r); h written only into out[:, :128].
__global__ __launch_bounds__(256) void k_gemm_lstm(const float* __restrict__ h_prev,
                                                   const float* __restrict__ r_prev,
                                                   const float* __restrict__ c_prev,
                                                   const float* __restrict__ Wc,
                                                   const float* __restrict__ b_ih,
                                                   const float* __restrict__ b_hh,
                                                   float* __restrict__ h_mirror) {
    __shared__ float As[128 * TS];
    __shared__ float Ws[64 * TS];
    int ct = blockIdx.y;
    int rb = blockIdx.x * 128;
    int tid = threadIdx.x;
    int tx = tid & 15, ty = tid >> 4;
    float acc[8][4];
#pragma unroll
    for (int i = 0; i < 8; ++i)
#pragma unroll
        for (int j = 0; j < 4; ++j) acc[i][j] = 0.0f;

    for (int kc = 0; kc < 8; ++kc) {
        const float* src = (kc < 4) ? h_prev : r_prev;
        int kbase = (kc & 3) * 32;
#pragma unroll
        for (int i = 0; i < 4; ++i) {
            int li = tid + i * 256;
            int row = li >> 3;
            int c4 = (li & 7) * 4;
            *(vf4*)&As[row * TS + c4] = *(const vf4*)(src + (size_t)(rb + row) * HDIM + kbase + c4);
        }
#pragma unroll
        for (int i = 0; i < 2; ++i) {
            int li = tid + i * 256;
            int col = li >> 3;
            int c4 = (li & 7) * 4;
            int g = ct * 16 + (col & 15) + 128 * (col >> 4);
            *(vf4*)&Ws[col * TS + c4] = *(const vf4*)(Wc + (size_t)g * 256 + kc * 32 + c4);
        }
        __syncthreads();
#pragma unroll
        for (int k = 0; k < 32; k += 4) {
            vf4 a[8], b[4];
#pragma unroll
            for (int i = 0; i < 8; ++i) a[i] = *(vf4*)&As[(ty + 16 * i) * TS + k];
#pragma unroll
            for (int j = 0; j < 4; ++j) b[j] = *(vf4*)&Ws[(tx + 16 * j) * TS + k];
#pragma unroll
            for (int i = 0; i < 8; ++i)
#pragma unroll
                for (int j = 0; j < 4; ++j) {
                    acc[i][j] += a[i].x * b[j].x + a[i].y * b[j].y +
                                 a[i].z * b[j].z + a[i].w * b[j].w;
                }
        }
        __syncthreads();
    }
    int hidx = ct * 16 + tx;
    float bi = b_ih[hidx] + b_hh[hidx];
    float bf = b_ih[HDIM + hidx] + b_hh[HDIM + hidx];
    float bg = b_ih[2 * HDIM + hidx] + b_hh[2 * HDIM + hidx];
    float bo = b_ih[3 * HDIM + hidx] + b_hh[3 * HDIM + hidx];
#pragma unroll
    for (int i = 0; i < 8; ++i) {
        int row = rb + ty + 16 * i;
        float gi = acc[i][0] + bi;
        float gf = acc[i][1] + bf;
        float gg = acc[i][2] + bg;
        float go = acc[i][3] + bo;
        float cp = c_prev[(size_t)row * HDIM + hidx];
        float cn = sigm(gf) * cp + sigm(gi) * ftanh(gg);
        float hn = sigm(go) * ftanh(cn);
        h_mirror[(size_t)row * 2 * HDIM + hidx] = hn;
    }
}

extern "C" void kernel_launch(void* const* d_in, const int* in_sizes, int n_in,
                              void* d_out, int out_size, void* d_ws, size_t ws_size,
                              hipStream_t stream) {
    const float* x = (const float*)d_in[0];
    const int* batch_vec = (const int*)d_in[1];
    const float* W_ih = (const float*)d_in[2];
    const float* W_hh = (const float*)d_in[3];
    const float* b_ih = (const float*)d_in[4];
    const float* b_hh = (const float*)d_in[5];
    float* out = (float*)d_out;

    int N = in_sizes[1];
    int B = out_size / (2 * HDIM);

    char* ws = (char*)d_ws;
    float* Wc = (float*)ws;   ws += (size_t)G4 * 2 * HDIM * 4;
    float* gh0 = (float*)ws;  ws += (size_t)G4 * 4;
    float* h_b = (float*)ws;  ws += (size_t)B * HDIM * 4;
    float* cbuf = (float*)ws; ws += (size_t)B * HDIM * 4;
    float* rbuf = (float*)ws; ws += (size_t)B * HDIM * 4;
    int* seg = (int*)ws;      ws += (size_t)(B + 1) * 4;
    ws = (char*)(((size_t)ws + 255) & ~(size_t)255);
    unsigned short* x16 = (unsigned short*)ws;  // N*128*2 = 256 MB

    k_setup<<<512, 256, 0, stream>>>(W_ih, W_hh, b_ih, b_hh, batch_vec, N, B, Wc, seg, gh0);

    dim3 ggrid(B / 128, 8);
    int ablk = (B + 15) / 16;  // quarter-per-segment: 16 segments per block
    k_attn_cvt<<<ablk, 256, 0, stream>>>(x, x16, b_ih, b_hh, seg, rbuf, B);
    k_gemm_lstm1<<<ggrid, 256, 0, stream>>>(rbuf, Wc, gh0, b_ih, b_hh, h_b, cbuf);
    k_attn_b16<<<ablk, 256, 0, stream>>>(x16, h_b, HDIM, seg, rbuf, HDIM, 0, B, 1);
    k_gemm_lstm<<<ggrid, 256, 0, stream>>>(h_b, rbuf, cbuf, Wc, b_ih, b_hh, out);
    k_attn_b16<<<ablk, 256, 0, stream>>>(x16, out, 2 * HDIM, seg, out, 2 * HDIM, HDIM, B, 0);
}